// Round 2
// baseline (365.211 us; speedup 1.0000x reference)
//
#include <hip/hip_runtime.h>
#include <hip/hip_fp16.h>
#include <math.h>
#include <stdint.h>
#include <stddef.h>

#define NLEVELS 16
#define HSIZE   32768
#define LOGH    15
#define RANKK   4
#define PRIME1  2654435761u
#define PRIME2  805459861u

#define BLK  1024
#define PTS  2                  // points per thread
#define PPB  (BLK * PTS)        // 2048 points per block

struct ResArr { float v[NLEVELS]; };

typedef __attribute__((address_space(1))) const uint32_t gu32;
typedef __attribute__((address_space(3))) uint32_t lu32;

// ---------------- Kernel 1: materialize LoRA tables as packed fp16x2 ----------------
__global__ void build_tables_k(const float* __restrict__ A, const float* __restrict__ B,
                               uint32_t* __restrict__ T) {
    int i = blockIdx.x * blockDim.x + threadIdx.x;
    if (i >= NLEVELS * HSIZE) return;
    int l = i >> LOGH;
    const float4 a = *reinterpret_cast<const float4*>(A + (size_t)i * RANKK);
    const float* b = B + l * (RANKK * 2);   // [r][f]
    float f0 = a.x * b[0] + a.y * b[2] + a.z * b[4] + a.w * b[6];
    float f1 = a.x * b[1] + a.y * b[3] + a.z * b[5] + a.w * b[7];
    __half2 h = __floats2half2_rn(f0, f1);
    T[i] = *reinterpret_cast<uint32_t*>(&h);
}

// ---------------- Kernel 2: all-levels-per-block encode, direct final layout -------
// grid = ceil(nPoints / PPB) blocks of 1024 threads. Each block:
//   for l in 0..15: stage level-l table (128 KiB fp16x2) into LDS via async DMA,
//                   gather+trilerp 2048 points, accumulate in registers.
//   Epilogue: write out[n*32 .. n*32+31] (one full 128B line per point, no RMW).
__global__ __launch_bounds__(BLK)
void encode_all_k(const float* __restrict__ x, const uint32_t* __restrict__ T,
                  float* __restrict__ out, int nPoints, ResArr res) {
    __shared__ uint32_t lds[HSIZE];          // 128 KiB of 160 KiB -> 1 block/CU
    const int t    = threadIdx.x;
    const int base = blockIdx.x * PPB;

    // ---- per-point setup (read x once, keep normalized coords in registers) ----
    int   n[PTS];
    bool  valid[PTS];
    float xn0[PTS], xn1[PTS], xn2[PTS];
#pragma unroll
    for (int p = 0; p < PTS; ++p) {
        n[p] = base + p * BLK + t;
        valid[p] = (n[p] < nPoints);
        int m = valid[p] ? n[p] : 0;
        xn0[p] = (x[3 * m + 0] + 1.0f) * 0.5f;   // bit-exact: (x+1)/2
        xn1[p] = (x[3 * m + 1] + 1.0f) * 0.5f;
        xn2[p] = (x[3 * m + 2] + 1.0f) * 0.5f;
    }

    float acc[PTS][NLEVELS * 2];
#pragma unroll
    for (int p = 0; p < PTS; ++p)
#pragma unroll
        for (int q = 0; q < NLEVELS * 2; ++q) acc[p][q] = 0.0f;

#pragma unroll
    for (int l = 0; l < NLEVELS; ++l) {
        if (l) __syncthreads();              // prior level's gathers complete
        // ---- async stage: global -> LDS, 16B per lane per issue ----
        {
            const uint32_t* Tl = T + (size_t)l * HSIZE;
#pragma unroll
            for (int k = 0; k < HSIZE / (BLK * 4); ++k) {   // 8 issues/thread
                int i = (k * BLK + t) * 4;
                __builtin_amdgcn_global_load_lds((gu32*)(Tl + i), (lu32*)(lds + i), 16, 0, 0);
            }
        }
        __syncthreads();                     // barrier drains vmcnt -> table ready

        const float r = res.v[l];
#pragma unroll
        for (int p = 0; p < PTS; ++p) {
            float xl0 = xn0[p] * r, xl1 = xn1[p] * r, xl2 = xn2[p] * r;
            float fl0 = floorf(xl0), fl1 = floorf(xl1), fl2 = floorf(xl2);
            float w0 = xl0 - fl0, w1 = xl1 - fl1, w2 = xl2 - fl2;
            uint32_t i0 = (uint32_t)fl0, i1 = (uint32_t)fl1, i2 = (uint32_t)fl2;

            uint32_t hx0 = i0,          hx1 = i0 + 1u;
            uint32_t hy0 = i1 * PRIME1, hy1 = hy0 + PRIME1;
            uint32_t hz0 = i2 * PRIME2, hz1 = hz0 + PRIME2;

            float w0a = 1.0f - w0, w1a = 1.0f - w1, w2a = 1.0f - w2;
            float wxy00 = w0a * w1a, wxy10 = w0 * w1a, wxy01 = w0a * w1, wxy11 = w0 * w1;

            float a0 = 0.0f, a1 = 0.0f;
#pragma unroll
            for (int c = 0; c < 8; ++c) {
                uint32_t h = ((c & 1) ? hx1 : hx0) ^ ((c & 2) ? hy1 : hy0) ^ ((c & 4) ? hz1 : hz0);
                uint32_t pk = lds[h & (HSIZE - 1)];
                __half2 h2 = *reinterpret_cast<__half2*>(&pk);
                float2 f = __half22float2(h2);
                float wxy = (c & 2) ? ((c & 1) ? wxy11 : wxy01) : ((c & 1) ? wxy10 : wxy00);
                float wc = wxy * ((c & 4) ? w2 : w2a);
                a0 = fmaf(f.x, wc, a0);
                a1 = fmaf(f.y, wc, a1);
            }
            acc[p][2 * l + 0] = a0;
            acc[p][2 * l + 1] = a1;
        }
    }

    // ---- epilogue: each point writes its own full 128B line ----
#pragma unroll
    for (int p = 0; p < PTS; ++p) {
        if (!valid[p]) continue;
        float4* dst = reinterpret_cast<float4*>(out + (size_t)n[p] * (NLEVELS * 2));
#pragma unroll
        for (int q = 0; q < 8; ++q)
            dst[q] = make_float4(acc[p][4 * q + 0], acc[p][4 * q + 1],
                                 acc[p][4 * q + 2], acc[p][4 * q + 3]);
    }
}

// ---------------- Fallback: on-the-fly LoRA dequant, global gather (tiny ws) --------
__global__ void encode_fallback_k(const float* __restrict__ x, const float* __restrict__ A,
                                  const float* __restrict__ B, float* __restrict__ out,
                                  int nPoints, ResArr res) {
    int n = blockIdx.x * blockDim.x + threadIdx.x;
    if (n >= nPoints) return;
    float xn0 = (x[3 * n + 0] + 1.0f) * 0.5f;
    float xn1 = (x[3 * n + 1] + 1.0f) * 0.5f;
    float xn2 = (x[3 * n + 2] + 1.0f) * 0.5f;
    for (int l = 0; l < NLEVELS; ++l) {
        float r = res.v[l];
        float xl0 = xn0 * r, xl1 = xn1 * r, xl2 = xn2 * r;
        float fl0 = floorf(xl0), fl1 = floorf(xl1), fl2 = floorf(xl2);
        float w0 = xl0 - fl0, w1 = xl1 - fl1, w2 = xl2 - fl2;
        uint32_t i0 = (uint32_t)fl0, i1 = (uint32_t)fl1, i2 = (uint32_t)fl2;
        uint32_t hx0 = i0,          hx1 = i0 + 1u;
        uint32_t hy0 = i1 * PRIME1, hy1 = hy0 + PRIME1;
        uint32_t hz0 = i2 * PRIME2, hz1 = hz0 + PRIME2;
        float w0a = 1.0f - w0, w1a = 1.0f - w1, w2a = 1.0f - w2;
        float wxy00 = w0a * w1a, wxy10 = w0 * w1a, wxy01 = w0a * w1, wxy11 = w0 * w1;
        const float* b = B + l * 8;
        float b00 = b[0], b01 = b[1], b10 = b[2], b11 = b[3];
        float b20 = b[4], b21 = b[5], b30 = b[6], b31 = b[7];
        float acc0 = 0.0f, acc1 = 0.0f;
#pragma unroll
        for (int c = 0; c < 8; ++c) {
            uint32_t h = ((c & 1) ? hx1 : hx0) ^ ((c & 2) ? hy1 : hy0) ^ ((c & 4) ? hz1 : hz0);
            uint32_t idx = h & (HSIZE - 1);
            float4 a = *reinterpret_cast<const float4*>(A + ((size_t)l * HSIZE + idx) * RANKK);
            float fe0 = a.x * b00 + a.y * b10 + a.z * b20 + a.w * b30;
            float fe1 = a.x * b01 + a.y * b11 + a.z * b21 + a.w * b31;
            float wxy = (c & 2) ? ((c & 1) ? wxy11 : wxy01) : ((c & 1) ? wxy10 : wxy00);
            float wc = wxy * ((c & 4) ? w2 : w2a);
            acc0 = fmaf(fe0, wc, acc0);
            acc1 = fmaf(fe1, wc, acc1);
        }
        out[(size_t)n * 32 + 2 * l + 0] = acc0;
        out[(size_t)n * 32 + 2 * l + 1] = acc1;
    }
}

extern "C" void kernel_launch(void* const* d_in, const int* in_sizes, int n_in,
                              void* d_out, int out_size, void* d_ws, size_t ws_size,
                              hipStream_t stream) {
    const float* x = (const float*)d_in[0];
    const float* A = (const float*)d_in[1];
    const float* B = (const float*)d_in[2];
    float* out = (float*)d_out;
    int nPoints = in_sizes[0] / 3;

    // numpy's resolution ladder, bit-exact via host double libm:
    // b = exp((log(512)-log(16))/15); res_l = float32(floor(16 * b**l))
    ResArr ra;
    {
        double b = exp((log(512.0) - log(16.0)) / 15.0);
        for (int l = 0; l < NLEVELS; ++l)
            ra.v[l] = (float)floor(16.0 * pow(b, (double)l));
    }

    const size_t tblBytes = (size_t)NLEVELS * HSIZE * sizeof(uint32_t);   // 2 MiB

    if (ws_size >= tblBytes) {
        uint32_t* T = (uint32_t*)d_ws;
        int nb1 = (NLEVELS * HSIZE + 255) / 256;
        build_tables_k<<<nb1, 256, 0, stream>>>(A, B, T);
        int blocks = (nPoints + PPB - 1) / PPB;   // 256 for N=524288
        encode_all_k<<<blocks, BLK, 0, stream>>>(x, T, out, nPoints, ra);
    } else {
        encode_fallback_k<<<(nPoints + 255) / 256, 256, 0, stream>>>(x, A, B, out, nPoints, ra);
    }
}

// Round 3
// 279.411 us; speedup vs baseline: 1.3071x; 1.3071x over previous
//
#include <hip/hip_runtime.h>
#include <hip/hip_fp16.h>
#include <math.h>
#include <stdint.h>
#include <stddef.h>

#define NLEVELS 16
#define HSIZE   32768
#define LOGH    15
#define RANKK   4
#define PRIME1  2654435761u
#define PRIME2  805459861u

#define BLK   1024
#define PTS   4                  // points per thread
#define PPB   (BLK * PTS)        // 4096 points per block
#define LGRP  4                  // levels per group (grid.y = NLEVELS/LGRP = 4)

struct ResArr { float v[NLEVELS]; };

typedef __attribute__((address_space(1))) const uint32_t gu32;
typedef __attribute__((address_space(3))) uint32_t lu32;

// ---------------- Kernel 1: materialize LoRA tables as packed fp16x2 ----------------
__global__ void build_tables_k(const float* __restrict__ A, const float* __restrict__ B,
                               uint32_t* __restrict__ T) {
    int i = blockIdx.x * blockDim.x + threadIdx.x;
    if (i >= NLEVELS * HSIZE) return;
    int l = i >> LOGH;
    const float4 a = *reinterpret_cast<const float4*>(A + (size_t)i * RANKK);
    const float* b = B + l * (RANKK * 2);   // [r][f]
    float f0 = a.x * b[0] + a.y * b[2] + a.z * b[4] + a.w * b[6];
    float f1 = a.x * b[1] + a.y * b[3] + a.z * b[5] + a.w * b[7];
    __half2 h = __floats2half2_rn(f0, f1);
    T[i] = *reinterpret_cast<uint32_t*>(&h);
}

// ---------------- Kernel 2: grouped encode -----------------------------------------
// grid = (nPoints/PPB, NLEVELS/LGRP). Block (cx, g) handles points
// [cx*PPB, cx*PPB+PPB) for levels [g*LGRP, g*LGRP+LGRP):
//   per level: async-stage the 128 KiB fp16x2 table into LDS, gather+trilerp,
//   accumulate in registers (PTS*LGRP*2 = 32 VGPRs of acc — no spill at cap 128).
// Epilogue: write out[n*32 + 2*l0 .. +8) = 32 contiguous bytes (full sectors).
__global__ __launch_bounds__(BLK, 4)
void encode_group_k(const float* __restrict__ x, const uint32_t* __restrict__ T,
                    float* __restrict__ out, int nPoints, ResArr res) {
    __shared__ uint32_t lds[HSIZE];          // 128 KiB -> 1 block/CU
    const int t    = threadIdx.x;
    const int base = blockIdx.x * PPB;
    const int l0   = blockIdx.y * LGRP;

    // ---- per-point setup: read x once, keep normalized coords in registers ----
    float xn0[PTS], xn1[PTS], xn2[PTS];
#pragma unroll
    for (int p = 0; p < PTS; ++p) {
        int n = base + p * BLK + t;
        int m = (n < nPoints) ? n : 0;
        xn0[p] = (x[3 * m + 0] + 1.0f) * 0.5f;   // bit-exact: (x+1)/2
        xn1[p] = (x[3 * m + 1] + 1.0f) * 0.5f;
        xn2[p] = (x[3 * m + 2] + 1.0f) * 0.5f;
    }

    float acc[PTS][LGRP * 2];
#pragma unroll
    for (int p = 0; p < PTS; ++p)
#pragma unroll
        for (int q = 0; q < LGRP * 2; ++q) acc[p][q] = 0.0f;

#pragma unroll
    for (int li = 0; li < LGRP; ++li) {
        const int l = l0 + li;
        if (li) __syncthreads();             // prior level's gathers complete
        // ---- async stage: global -> LDS, 16B per lane per issue (8 issues) ----
        {
            const uint32_t* Tl = T + (size_t)l * HSIZE;
#pragma unroll
            for (int k = 0; k < HSIZE / (BLK * 4); ++k) {
                int i = (k * BLK + t) * 4;
                __builtin_amdgcn_global_load_lds((gu32*)(Tl + i), (lu32*)(lds + i), 16, 0, 0);
            }
        }
        __syncthreads();                     // drains vmcnt -> table ready

        const float r = res.v[l];
#pragma unroll
        for (int p = 0; p < PTS; ++p) {
            float xl0 = xn0[p] * r, xl1 = xn1[p] * r, xl2 = xn2[p] * r;
            float fl0 = floorf(xl0), fl1 = floorf(xl1), fl2 = floorf(xl2);
            float w0 = xl0 - fl0, w1 = xl1 - fl1, w2 = xl2 - fl2;
            uint32_t i0 = (uint32_t)fl0, i1 = (uint32_t)fl1, i2 = (uint32_t)fl2;

            uint32_t hx0 = i0,          hx1 = i0 + 1u;
            uint32_t hy0 = i1 * PRIME1, hy1 = hy0 + PRIME1;
            uint32_t hz0 = i2 * PRIME2, hz1 = hz0 + PRIME2;

            float w0a = 1.0f - w0, w1a = 1.0f - w1, w2a = 1.0f - w2;
            float wxy00 = w0a * w1a, wxy10 = w0 * w1a, wxy01 = w0a * w1, wxy11 = w0 * w1;

            float a0 = 0.0f, a1 = 0.0f;
#pragma unroll
            for (int c = 0; c < 8; ++c) {
                uint32_t h = ((c & 1) ? hx1 : hx0) ^ ((c & 2) ? hy1 : hy0) ^ ((c & 4) ? hz1 : hz0);
                uint32_t pk = lds[h & (HSIZE - 1)];
                __half2 h2 = *reinterpret_cast<__half2*>(&pk);
                float2 f = __half22float2(h2);
                float wxy = (c & 2) ? ((c & 1) ? wxy11 : wxy01) : ((c & 1) ? wxy10 : wxy00);
                float wc = wxy * ((c & 4) ? w2 : w2a);
                a0 = fmaf(f.x, wc, a0);
                a1 = fmaf(f.y, wc, a1);
            }
            acc[p][2 * li + 0] = a0;
            acc[p][2 * li + 1] = a1;
        }
    }

    // ---- epilogue: each point writes its group's 32 contiguous bytes ----
#pragma unroll
    for (int p = 0; p < PTS; ++p) {
        int n = base + p * BLK + t;
        if (n >= nPoints) continue;
        float* dst = out + (size_t)n * (NLEVELS * 2) + 2 * l0;
        *reinterpret_cast<float4*>(dst)     = make_float4(acc[p][0], acc[p][1], acc[p][2], acc[p][3]);
        *reinterpret_cast<float4*>(dst + 4) = make_float4(acc[p][4], acc[p][5], acc[p][6], acc[p][7]);
    }
}

// ---------------- Fallback: on-the-fly LoRA dequant, global gather (tiny ws) --------
__global__ void encode_fallback_k(const float* __restrict__ x, const float* __restrict__ A,
                                  const float* __restrict__ B, float* __restrict__ out,
                                  int nPoints, ResArr res) {
    int n = blockIdx.x * blockDim.x + threadIdx.x;
    if (n >= nPoints) return;
    float xn0 = (x[3 * n + 0] + 1.0f) * 0.5f;
    float xn1 = (x[3 * n + 1] + 1.0f) * 0.5f;
    float xn2 = (x[3 * n + 2] + 1.0f) * 0.5f;
    for (int l = 0; l < NLEVELS; ++l) {
        float r = res.v[l];
        float xl0 = xn0 * r, xl1 = xn1 * r, xl2 = xn2 * r;
        float fl0 = floorf(xl0), fl1 = floorf(xl1), fl2 = floorf(xl2);
        float w0 = xl0 - fl0, w1 = xl1 - fl1, w2 = xl2 - fl2;
        uint32_t i0 = (uint32_t)fl0, i1 = (uint32_t)fl1, i2 = (uint32_t)fl2;
        uint32_t hx0 = i0,          hx1 = i0 + 1u;
        uint32_t hy0 = i1 * PRIME1, hy1 = hy0 + PRIME1;
        uint32_t hz0 = i2 * PRIME2, hz1 = hz0 + PRIME2;
        float w0a = 1.0f - w0, w1a = 1.0f - w1, w2a = 1.0f - w2;
        float wxy00 = w0a * w1a, wxy10 = w0 * w1a, wxy01 = w0a * w1, wxy11 = w0 * w1;
        const float* b = B + l * 8;
        float b00 = b[0], b01 = b[1], b10 = b[2], b11 = b[3];
        float b20 = b[4], b21 = b[5], b30 = b[6], b31 = b[7];
        float acc0 = 0.0f, acc1 = 0.0f;
#pragma unroll
        for (int c = 0; c < 8; ++c) {
            uint32_t h = ((c & 1) ? hx1 : hx0) ^ ((c & 2) ? hy1 : hy0) ^ ((c & 4) ? hz1 : hz0);
            uint32_t idx = h & (HSIZE - 1);
            float4 a = *reinterpret_cast<const float4*>(A + ((size_t)l * HSIZE + idx) * RANKK);
            float fe0 = a.x * b00 + a.y * b10 + a.z * b20 + a.w * b30;
            float fe1 = a.x * b01 + a.y * b11 + a.z * b21 + a.w * b31;
            float wxy = (c & 2) ? ((c & 1) ? wxy11 : wxy01) : ((c & 1) ? wxy10 : wxy00);
            float wc = wxy * ((c & 4) ? w2 : w2a);
            acc0 = fmaf(fe0, wc, acc0);
            acc1 = fmaf(fe1, wc, acc1);
        }
        out[(size_t)n * 32 + 2 * l + 0] = acc0;
        out[(size_t)n * 32 + 2 * l + 1] = acc1;
    }
}

extern "C" void kernel_launch(void* const* d_in, const int* in_sizes, int n_in,
                              void* d_out, int out_size, void* d_ws, size_t ws_size,
                              hipStream_t stream) {
    const float* x = (const float*)d_in[0];
    const float* A = (const float*)d_in[1];
    const float* B = (const float*)d_in[2];
    float* out = (float*)d_out;
    int nPoints = in_sizes[0] / 3;

    // numpy's resolution ladder, bit-exact via host double libm:
    // b = exp((log(512)-log(16))/15); res_l = float32(floor(16 * b**l))
    ResArr ra;
    {
        double b = exp((log(512.0) - log(16.0)) / 15.0);
        for (int l = 0; l < NLEVELS; ++l)
            ra.v[l] = (float)floor(16.0 * pow(b, (double)l));
    }

    const size_t tblBytes = (size_t)NLEVELS * HSIZE * sizeof(uint32_t);   // 2 MiB

    if (ws_size >= tblBytes) {
        uint32_t* T = (uint32_t*)d_ws;
        int nb1 = (NLEVELS * HSIZE + 255) / 256;
        build_tables_k<<<nb1, 256, 0, stream>>>(A, B, T);
        int chunks = (nPoints + PPB - 1) / PPB;           // 128 for N=524288
        dim3 grid(chunks, NLEVELS / LGRP);                // (128, 4) = 512 blocks
        encode_group_k<<<grid, BLK, 0, stream>>>(x, T, out, nPoints, ra);
    } else {
        encode_fallback_k<<<(nPoints + 255) / 256, 256, 0, stream>>>(x, A, B, out, nPoints, ra);
    }
}